// Round 2
// baseline (28.922 us; speedup 1.0000x reference)
//
#include <hip/hip_runtime.h>

// Aggregation (SAN-style): out[n,c,l] = sum_kk input_pad[n,c,tap(l,kk)] * weight[n, c/8, kk, l]
// N=8, C=256, Cw=32, share=8, K=3, H=W=56, L=3136. All fp32.
// Each thread computes 4 consecutive w-positions for 8 shared channels (32 outputs).

#define HH 56
#define WW 56
#define LL 3136
#define CW 32
#define SHARE 8
#define CC 256
#define NN 8
#define W4 14                      // WW / 4
#define TPOS (HH * W4)             // 784 thread-positions per (n,g)
#define TOTAL (TPOS * CW * NN)     // 200704 total threads

__global__ __launch_bounds__(256) void agg_kernel(const float* __restrict__ in,
                                                  const float* __restrict__ wt,
                                                  float* __restrict__ out) {
    const unsigned idx = blockIdx.x * 256u + threadIdx.x;
    if (idx >= TOTAL) return;
    const unsigned t  = idx % TPOS;          // position within (n,g)
    const unsigned ng = idx / TPOS;          // n*CW + g
    const unsigned g  = ng % CW;
    const unsigned n  = ng / CW;
    const unsigned h  = t / W4;
    const unsigned w  = (t - h * W4) * 4;
    const unsigned l  = h * WW + w;          // 16B-aligned (w % 4 == 0)

    // 9 per-location weight vectors: wt[n,g,kk, l..l+3], stride LL between taps.
    const float* wp = wt + (((size_t)n * CW + g) * 9) * LL + l;
    float4 wv[9];
#pragma unroll
    for (int kk = 0; kk < 9; ++kk) wv[kk] = *(const float4*)(wp + (size_t)kk * LL);

    const bool h_up = (h > 0), h_dn = (h < HH - 1);
    const bool w_lt = (w > 0), w_rt = (w + 4 < WW);

    const unsigned c0 = g * SHARE;
    const float* ip = in  + ((size_t)n * CC + c0) * LL + l;
    float*       op = out + ((size_t)n * CC + c0) * LL + l;

#pragma unroll
    for (int s = 0; s < SHARE; ++s) {
        const float* p = ip + (size_t)s * LL;
        float a0 = 0.f, a1 = 0.f, a2 = 0.f, a3 = 0.f;
#pragma unroll
        for (int r = 0; r < 3; ++r) {                 // kernel row: dh = r-1
            const bool rv = (r == 0) ? h_up : ((r == 2) ? h_dn : true);
            float row0, row1, row2, row3, row4, row5; // covers w-1 .. w+4
            if (rv) {
                const float* q = p + (r - 1) * WW;
                const float4 c = *(const float4*)q;   // aligned
                row0 = w_lt ? q[-1] : 0.f;
                row1 = c.x; row2 = c.y; row3 = c.z; row4 = c.w;
                row5 = w_rt ? q[4] : 0.f;
            } else {
                row0 = row1 = row2 = row3 = row4 = row5 = 0.f;
            }
            // dw = -1, 0, +1  ->  taps kk = 3r, 3r+1, 3r+2
            const float4 wa = wv[3 * r + 0];
            const float4 wb = wv[3 * r + 1];
            const float4 wc = wv[3 * r + 2];
            a0 = fmaf(row0, wa.x, a0); a1 = fmaf(row1, wa.y, a1);
            a2 = fmaf(row2, wa.z, a2); a3 = fmaf(row3, wa.w, a3);
            a0 = fmaf(row1, wb.x, a0); a1 = fmaf(row2, wb.y, a1);
            a2 = fmaf(row3, wb.z, a2); a3 = fmaf(row4, wb.w, a3);
            a0 = fmaf(row2, wc.x, a0); a1 = fmaf(row3, wc.y, a1);
            a2 = fmaf(row4, wc.z, a2); a3 = fmaf(row5, wc.w, a3);
        }
        *(float4*)(op + (size_t)s * LL) = make_float4(a0, a1, a2, a3);
    }
}

extern "C" void kernel_launch(void* const* d_in, const int* in_sizes, int n_in,
                              void* d_out, int out_size, void* d_ws, size_t ws_size,
                              hipStream_t stream) {
    const float* in = (const float*)d_in[0];
    const float* wt = (const float*)d_in[1];
    float* out = (float*)d_out;
    agg_kernel<<<dim3((TOTAL + 255) / 256), dim3(256), 0, stream>>>(in, wt, out);
}

// Round 3
// 25.365 us; speedup vs baseline: 1.1402x; 1.1402x over previous
//
#include <hip/hip_runtime.h>

// Aggregation (SAN-style): out[n,c,l] = sum_kk input_pad[n,c,tap(l,kk)] * weight[n, c/8, kk, l]
// N=8, C=256, Cw=32, share=8, K=3, H=W=56, L=3136. All fp32.
// Each thread computes 4 consecutive w-positions for 8 shared channels (32 outputs).
// Block = 64 threads (1 wave) -> 3136 blocks: fine-grained, no per-CU tail quantization.

#define HH 56
#define WW 56
#define LL 3136
#define CW 32
#define SHARE 8
#define CC 256
#define NN 8
#define W4 14                      // WW / 4
#define TPOS (HH * W4)             // 784 thread-positions per (n,g)
#define TOTAL (TPOS * CW * NN)     // 200704 total threads = 3136 blocks of 64

__global__ __launch_bounds__(64) void agg_kernel(const float* __restrict__ in,
                                                 const float* __restrict__ wt,
                                                 float* __restrict__ out) {
    const unsigned idx = blockIdx.x * 64u + threadIdx.x;
    const unsigned t  = idx % TPOS;          // position within (n,g)
    const unsigned ng = idx / TPOS;          // n*CW + g
    const unsigned g  = ng % CW;
    const unsigned n  = ng / CW;
    const unsigned h  = t / W4;
    const unsigned w  = (t - h * W4) * 4;
    const unsigned l  = h * WW + w;          // 16B-aligned (w % 4 == 0)

    // 9 per-location weight vectors: wt[n,g,kk, l..l+3], stride LL between taps.
    const float* wp = wt + (((size_t)n * CW + g) * 9) * LL + l;
    float4 wv[9];
#pragma unroll
    for (int kk = 0; kk < 9; ++kk) wv[kk] = *(const float4*)(wp + (size_t)kk * LL);

    const bool h_up = (h > 0), h_dn = (h < HH - 1);
    const bool w_lt = (w > 0), w_rt = (w + 4 < WW);

    const unsigned c0 = g * SHARE;
    const float* ip = in  + ((size_t)n * CC + c0) * LL + l;
    float*       op = out + ((size_t)n * CC + c0) * LL + l;

#pragma unroll
    for (int s = 0; s < SHARE; ++s) {
        const float* p = ip + (size_t)s * LL;
        float a0 = 0.f, a1 = 0.f, a2 = 0.f, a3 = 0.f;
#pragma unroll
        for (int r = 0; r < 3; ++r) {                 // kernel row: dh = r-1
            const bool rv = (r == 0) ? h_up : ((r == 2) ? h_dn : true);
            float row0, row1, row2, row3, row4, row5; // covers w-1 .. w+4
            if (rv) {
                const float* q = p + (r - 1) * WW;
                const float4 c = *(const float4*)q;   // aligned
                row0 = w_lt ? q[-1] : 0.f;
                row1 = c.x; row2 = c.y; row3 = c.z; row4 = c.w;
                row5 = w_rt ? q[4] : 0.f;
            } else {
                row0 = row1 = row2 = row3 = row4 = row5 = 0.f;
            }
            // dw = -1, 0, +1  ->  taps kk = 3r, 3r+1, 3r+2
            const float4 wa = wv[3 * r + 0];
            const float4 wb = wv[3 * r + 1];
            const float4 wc = wv[3 * r + 2];
            a0 = fmaf(row0, wa.x, a0); a1 = fmaf(row1, wa.y, a1);
            a2 = fmaf(row2, wa.z, a2); a3 = fmaf(row3, wa.w, a3);
            a0 = fmaf(row1, wb.x, a0); a1 = fmaf(row2, wb.y, a1);
            a2 = fmaf(row3, wb.z, a2); a3 = fmaf(row4, wb.w, a3);
            a0 = fmaf(row2, wc.x, a0); a1 = fmaf(row3, wc.y, a1);
            a2 = fmaf(row4, wc.z, a2); a3 = fmaf(row5, wc.w, a3);
        }
        *(float4*)(op + (size_t)s * LL) = make_float4(a0, a1, a2, a3);
    }
}

extern "C" void kernel_launch(void* const* d_in, const int* in_sizes, int n_in,
                              void* d_out, int out_size, void* d_ws, size_t ws_size,
                              hipStream_t stream) {
    const float* in = (const float*)d_in[0];
    const float* wt = (const float*)d_in[1];
    float* out = (float*)d_out;
    agg_kernel<<<dim3(TOTAL / 64), dim3(64), 0, stream>>>(in, wt, out);
}

// Round 4
// 25.317 us; speedup vs baseline: 1.1424x; 1.0019x over previous
//
#include <hip/hip_runtime.h>

// Aggregation (SAN-style): out[n,c,l] = sum_kk input_pad[n,c,tap(l,kk)] * weight[n, c/8, kk, l]
// N=8, C=256, Cw=32, share=8, K=3, H=W=56, L=3136. All fp32.
//
// R4 layout: block = 256 threads = 4 waves, all covering the SAME 64 spatial
// quads (4-wide float4 positions); wave w handles channel pair c0 = g*8 + w*2.
// -> 3328 blocks (13/CU exact), 13312 waves (R1-level occupancy) with R3's
//    16B/lane vectorized accesses. Weight float4s re-read by the block's 4
//    waves hit L1 (same CU).

#define HH 56
#define WW 56
#define LL 3136
#define CW 32
#define CC 256
#define NN 8
#define W4 14
#define TPOS (HH * W4)   // 784 quads per plane
#define NB 13            // ceil(784/64) quad-blocks per (n,g)

__global__ __launch_bounds__(256) void agg_kernel(const float* __restrict__ in,
                                                  const float* __restrict__ wt,
                                                  float* __restrict__ out) {
    const unsigned b    = blockIdx.x;
    const unsigned ng   = b / NB;
    const unsigned qb   = (b - ng * NB) * 64u;
    const unsigned lane = threadIdx.x & 63u;
    const unsigned sq   = threadIdx.x >> 6;   // wave id 0..3 -> channel pair
    const unsigned q    = qb + lane;
    if (q >= TPOS) return;                    // only in the 13th block
    const unsigned g = ng % CW;
    const unsigned n = ng / CW;
    const unsigned h = q / W4;
    const unsigned w = (q - h * W4) * 4u;
    const unsigned l = h * WW + w;            // 16B-aligned

    const bool h_up = (h > 0), h_dn = (h < HH - 1);
    const bool w_lt = (w > 0), w_rt = (w + 4 < WW);

    const float* wp = wt + (((size_t)n * CW + g) * 9) * LL + l;
    const unsigned c0 = g * 8u + sq * 2u;
    const float* ip = in  + ((size_t)n * CC + c0) * LL + l;
    float*       op = out + ((size_t)n * CC + c0) * LL + l;

    float4 acc[2];
    acc[0] = make_float4(0.f, 0.f, 0.f, 0.f);
    acc[1] = make_float4(0.f, 0.f, 0.f, 0.f);

#pragma unroll
    for (int r = 0; r < 3; ++r) {             // kernel row: dh = r-1
        const bool rv = (r == 0) ? h_up : ((r == 2) ? h_dn : true);
        const float4 wa = *(const float4*)(wp + (size_t)(3 * r + 0) * LL);
        const float4 wb = *(const float4*)(wp + (size_t)(3 * r + 1) * LL);
        const float4 wc = *(const float4*)(wp + (size_t)(3 * r + 2) * LL);
#pragma unroll
        for (int s = 0; s < 2; ++s) {         // the wave's 2 channels
            float r0, r1, r2, r3, r4, r5;     // covers w-1 .. w+4
            if (rv) {
                const float* qp = ip + (size_t)s * LL + (r - 1) * WW;
                const float4 c = *(const float4*)qp;   // aligned
                r0 = w_lt ? qp[-1] : 0.f;
                r1 = c.x; r2 = c.y; r3 = c.z; r4 = c.w;
                r5 = w_rt ? qp[4] : 0.f;
            } else {
                r0 = r1 = r2 = r3 = r4 = r5 = 0.f;
            }
            acc[s].x = fmaf(r0, wa.x, acc[s].x);
            acc[s].y = fmaf(r1, wa.y, acc[s].y);
            acc[s].z = fmaf(r2, wa.z, acc[s].z);
            acc[s].w = fmaf(r3, wa.w, acc[s].w);
            acc[s].x = fmaf(r1, wb.x, acc[s].x);
            acc[s].y = fmaf(r2, wb.y, acc[s].y);
            acc[s].z = fmaf(r3, wb.z, acc[s].z);
            acc[s].w = fmaf(r4, wb.w, acc[s].w);
            acc[s].x = fmaf(r2, wc.x, acc[s].x);
            acc[s].y = fmaf(r3, wc.y, acc[s].y);
            acc[s].z = fmaf(r4, wc.z, acc[s].z);
            acc[s].w = fmaf(r5, wc.w, acc[s].w);
        }
    }
    *(float4*)op = acc[0];
    *(float4*)(op + LL) = acc[1];
}

extern "C" void kernel_launch(void* const* d_in, const int* in_sizes, int n_in,
                              void* d_out, int out_size, void* d_ws, size_t ws_size,
                              hipStream_t stream) {
    const float* in = (const float*)d_in[0];
    const float* wt = (const float*)d_in[1];
    float* out = (float*)d_out;
    agg_kernel<<<dim3(NN * CW * NB), dim3(256), 0, stream>>>(in, wt, out);
}

// Round 5
// 24.839 us; speedup vs baseline: 1.1644x; 1.0193x over previous
//
#include <hip/hip_runtime.h>

// Aggregation (SAN-style): out[n,c,l] = sum_kk input_pad[n,c,tap(l,kk)] * weight[n, c/8, kk, l]
// N=8, C=256, Cw=32, share=8, K=3, H=W=56, L=3136. All fp32.
//
// R5: LDS-staged stencil. Block = 256 thr = one (n, g, 14-row band).
// Grid = 8*32*4 = 1024 blocks = exactly 4 blocks/CU (zero tail).
// Stage 8ch x 16 LDS rows (2 zero halo rows, zero halo cols) -> compute reads
// taps from LDS only: no L1 tap re-reads, no unaligned gathers, no edge branches.

#define HH 56
#define WW 56
#define LL 3136
#define CW 32
#define CC 256
#define NN 8
#define RBAND 14
#define SROWS 16                 // RBAND + 2 halo rows
#define LDSTR 68                 // floats per LDS row (bank spread; 68%32=4)
#define CHSTR (SROWS * LDSTR)    // 1088 floats per channel
#define COLOFF 4                 // data cols 4..59; col 3 / col 60 = zero halo

__global__ __launch_bounds__(256) void agg_kernel(const float* __restrict__ in,
                                                  const float* __restrict__ wt,
                                                  float* __restrict__ out) {
    __shared__ float lds[8 * CHSTR];        // 34816 B

    const unsigned b    = blockIdx.x;
    const unsigned band = b & 3u;
    const unsigned ng   = b >> 2;
    const unsigned g    = ng & 31u;
    const unsigned n    = ng >> 5;
    const unsigned t    = threadIdx.x;
    const unsigned h0   = band * RBAND;

    // ---- compute-phase indices (threads >=196 clamp; they skip compute) ----
    const unsigned qc = (t < 196u) ? t : 195u;
    const unsigned hb = qc / 14u;                  // 0..13 row in band
    const unsigned wq = (qc - hb * 14u) * 4u;      // 0..52, 16B-aligned
    const unsigned h  = h0 + hb;
    const unsigned lq = h * WW + wq;

    // ---- early weight loads: 9 x float4, coalesced, long-latency in flight ----
    const float* wp = wt + (((size_t)n * CW + g) * 9u) * LL + lq;
    float4 wv[9];
#pragma unroll
    for (int kk = 0; kk < 9; ++kk) wv[kk] = *(const float4*)(wp + (size_t)kk * LL);

    // ---- stage input: group = t/32 -> channel, lane = t%32 ----
    // Each channel: 16 rows x 56 = 224 float4 loads; lane does 7.
    const unsigned grp  = t >> 5;
    const unsigned lane = t & 31u;
    const unsigned c    = g * 8u + grp;
    const float*   ip   = in + ((size_t)n * CC + c) * LL;
#pragma unroll
    for (int j = 0; j < 7; ++j) {
        const unsigned k    = lane + j * 32u;      // 0..223
        const unsigned grow = k / 14u;             // LDS row 0..15
        const unsigned gcol = (k - grow * 14u) * 4u;
        const int      gr   = (int)(h0 + grow) - 1;    // global row, -1..56
        float4 v = make_float4(0.f, 0.f, 0.f, 0.f);
        if ((unsigned)gr < HH) v = *(const float4*)(ip + (size_t)gr * WW + gcol);
        *(float4*)&lds[grp * CHSTR + grow * LDSTR + COLOFF + gcol] = v;
    }
    // zero halo cols 3 and 60: 8ch * 16rows * 2cols = 256 writes, one per thread
    {
        const unsigned ch   = t >> 5;
        const unsigned rr   = (t >> 1) & 15u;
        const unsigned ccol = (t & 1u) ? 60u : 3u;
        lds[ch * CHSTR + rr * LDSTR + ccol] = 0.f;
    }
    __syncthreads();

    if (t < 196u) {
        float* op = out + ((size_t)n * CC + g * 8u) * LL + lq;
#pragma unroll
        for (int ch = 0; ch < 8; ++ch) {
            float4 a = make_float4(0.f, 0.f, 0.f, 0.f);
#pragma unroll
            for (int dr = 0; dr < 3; ++dr) {       // LDS rows hb..hb+2 = global h-1..h+1
                const float* lp = &lds[ch * CHSTR + (hb + dr) * LDSTR + COLOFF + wq];
                const float  r0 = lp[-1];
                const float4 c4 = *(const float4*)lp;   // 16B-aligned
                const float  r5 = lp[4];
                const float4 wa = wv[3 * dr + 0];
                const float4 wb = wv[3 * dr + 1];
                const float4 wc = wv[3 * dr + 2];
                a.x = fmaf(r0,   wa.x, a.x);
                a.y = fmaf(c4.x, wa.y, a.y);
                a.z = fmaf(c4.y, wa.z, a.z);
                a.w = fmaf(c4.z, wa.w, a.w);
                a.x = fmaf(c4.x, wb.x, a.x);
                a.y = fmaf(c4.y, wb.y, a.y);
                a.z = fmaf(c4.z, wb.z, a.z);
                a.w = fmaf(c4.w, wb.w, a.w);
                a.x = fmaf(c4.y, wc.x, a.x);
                a.y = fmaf(c4.z, wc.y, a.y);
                a.z = fmaf(c4.w, wc.z, a.z);
                a.w = fmaf(r5,   wc.w, a.w);
            }
            *(float4*)(op + (size_t)ch * LL) = a;
        }
    }
}

extern "C" void kernel_launch(void* const* d_in, const int* in_sizes, int n_in,
                              void* d_out, int out_size, void* d_ws, size_t ws_size,
                              hipStream_t stream) {
    const float* in = (const float*)d_in[0];
    const float* wt = (const float*)d_in[1];
    float* out = (float*)d_out;
    agg_kernel<<<dim3(NN * CW * 4), dim3(256), 0, stream>>>(in, wt, out);
}